// Round 4
// baseline (49.674 us; speedup 1.0000x reference)
//
#include <hip/hip_runtime.h>

// YOLOv3 loss on MI355X — round 4: fully fused.
// Graph = 1 tiny memset (acc+counter) + 1 kernel.
// blocks [0,600):   correct — one wave per (scale,b,t); per-target record is
//                   recomputed IN-REGISTER (lane l = target l), ballots/shuffles
//                   reconstruct mask/nm/last-writer/class-union; coalesced
//                   85-channel gather; lane-parallel class BCE.
// blocks [600,1266): noobj — gather channel 4 of every cell (1 cell/thread).
// Last finished block (atomic counter) combines the 27 partials -> d_out[0].

#define NB 16      // batch
#define NT 50      // targets per batch
#define NA 3       // anchors
#define NC 80      // classes
#define NCORR 600  // correct blocks (600*4 waves = 2400 = 3*16*50)
#define NBLK 1266  // total blocks (600 + ceil(170352/256))

__device__ __forceinline__ float bce0(float p) { return -log1pf(-p); } // target 0
__device__ __forceinline__ float bce1(float p) { return -logf(p); }    // target 1

// acc layout: [scale*9 + j], j: 0..3 mse, 4 obj, 5 noobj, 6 cls, 7 n_pos, 8 n_zeroed
__global__ __launch_bounds__(256) void fused_kernel(
    const float* __restrict__ o13,
    const float* __restrict__ o26,
    const float* __restrict__ o52,
    const float* __restrict__ targets,
    const float* __restrict__ a13,
    const float* __restrict__ a26,
    const float* __restrict__ a52,
    float* __restrict__ acc,        // [27], zeroed by memset node
    unsigned* __restrict__ counter, // [1], zeroed by memset node
    float* __restrict__ outp)
{
    __shared__ float sacc[27];
    __shared__ float red[4][3];
    __shared__ int sflag;

    int lane = threadIdx.x & 63;
    int wvid = threadIdx.x >> 6;

    if (blockIdx.x < NCORR) {
        // ---------------- correct region ----------------
        if (threadIdx.x < 27) sacc[threadIdx.x] = 0.0f;
        __syncthreads();

        int wid = blockIdx.x * 4 + wvid;            // 0..2399
        int scale = wid / (NB * NT);
        int rem   = wid - scale * (NB * NT);
        int b = rem / NT, t = rem - b * NT;

        int G = (scale == 0) ? 13 : (scale == 1) ? 26 : 52;
        const float* out  = (scale == 0) ? o13 : (scale == 1) ? o26 : o52;
        const float* anch = (scale == 0) ? a13 : (scale == 1) ? a26 : a52;

        // in-register build: lane l computes target l's record
        unsigned mt = 0xFFFFFFFFu;
        float tx = 0.0f, ty = 0.0f, tw = 0.0f, th = 0.0f;
        {
            int li = (lane < NT) ? lane : NT - 1;   // clamped: valid addr, masked below
            const float* tg = targets + ((size_t)b * NT + li) * 5;
            float x1 = tg[0], y1 = tg[1], x2 = tg[2], y2 = tg[3];
            int cls = (int)tg[4];
            float gf = (float)G;
            float bx = 0.5f * (x1 + x2) * gf;
            float by = 0.5f * (y1 + y2) * gf;
            float bw = (x2 - x1) * gf;
            float bh = (y2 - y1) * gf;
            int best = 0; float bestiou = -1.0f, aw_b = 1.0f, ah_b = 1.0f;
            unsigned nmz = 0;
            #pragma unroll
            for (int a = 0; a < NA; ++a) {
                float aw = anch[2 * a], ah = anch[2 * a + 1];
                float inter = fminf(aw, bw) * fminf(ah, bh);
                float uni = 1e-8f + aw * ah + bw * bh - inter;
                float iou = inter / uni;
                if (iou > 0.5f) nmz |= (1u << a);
                if (iou > bestiou) { bestiou = iou; best = a; aw_b = aw; ah_b = ah; }
            }
            int gi = (int)bx; gi = gi < 0 ? 0 : (gi > G - 1 ? G - 1 : gi);
            int gj = (int)by; gj = gj < 0 ? 0 : (gj > G - 1 ? G - 1 : gj);
            tx = bx - floorf(bx);
            ty = by - floorf(by);
            tw = logf(bw / aw_b);
            th = logf(bh / ah_b);
            if (lane < NT)
                mt = (unsigned)gi | ((unsigned)gj << 6) | ((unsigned)best << 12)
                   | ((unsigned)cls << 14) | (nmz << 21);
        }

        unsigned key_lane = mt & 0xFFFu;
        unsigned key_t = __shfl(key_lane, t);
        unsigned long long match = __ballot(lane < NT && key_lane == key_t);
        bool canon = ((match & ((1ull << t) - 1ull)) == 0ull);   // wave-uniform

        if (canon) {
            int gi = key_t & 63, gj = (key_t >> 6) & 63;
            #pragma unroll
            for (int a = 0; a < NA; ++a) {
                unsigned long long bestmask =
                    __ballot(lane < NT && key_lane == key_t && (int)((mt >> 12) & 3u) == a);
                unsigned long long nmzmask =
                    __ballot(lane < NT && key_lane == key_t && ((mt >> (21 + a)) & 1u));
                bool pos = bestmask != 0ull;
                bool zeroed = pos || (nmzmask != 0ull);
                if (!zeroed) continue;                  // wave-uniform

                const float* pc = out + (((size_t)(b * NA + a) * G + gj) * G + gi) * 85;
                float vlo = pc[lane];                   // channels 0..63, coalesced
                if (lane == 4) {                        // noobj correction
                    atomicAdd(&sacc[scale * 9 + 5], -bce0(vlo));
                    atomicAdd(&sacc[scale * 9 + 8], 1.0f);
                }
                if (pos) {
                    float vhi = (lane < 21) ? pc[64 + lane] : 0.0f;  // ch 64..84
                    int lastt = 63 - __clzll(bestmask);  // last-write-wins
                    float ltx = __shfl(tx, lastt), lty = __shfl(ty, lastt);
                    float ltw = __shfl(tw, lastt), lth = __shfl(th, lastt);
                    // class-bit union across matching-best lanes
                    unsigned c0 = 0, c1 = 0, c2 = 0;
                    if ((bestmask >> lane) & 1ull) {
                        int c = (mt >> 14) & 127;
                        if (c < 32) c0 = 1u << c;
                        else if (c < 64) c1 = 1u << (c - 32);
                        else c2 = 1u << (c - 64);
                    }
                    #pragma unroll
                    for (int off = 32; off; off >>= 1) {
                        c0 |= __shfl_xor(c0, off);
                        c1 |= __shfl_xor(c1, off);
                        c2 |= __shfl_xor(c2, off);
                    }
                    // lane-parallel class BCE: lane -> channel lane and 64+lane
                    float cls = 0.0f;
                    if (lane >= 5) {
                        int c = lane - 5;               // 0..58
                        unsigned w = (c < 32) ? c0 : c1;
                        cls += ((w >> (c & 31)) & 1u) ? bce1(vlo) : bce0(vlo);
                    }
                    if (lane < 21) {
                        int c = lane + 59;              // 59..79
                        unsigned w = (c < 64) ? c1 : c2;
                        cls += ((w >> (c & 31)) & 1u) ? bce1(vhi) : bce0(vhi);
                    }
                    #pragma unroll
                    for (int off = 32; off; off >>= 1) cls += __shfl_xor(cls, off);
                    if (lane == 0) {
                        atomicAdd(&sacc[scale * 9 + 6], cls);
                        atomicAdd(&sacc[scale * 9 + 7], 1.0f);
                    }
                    if (lane < 4) {                     // mse terms
                        float tv = (lane == 0) ? ltx : (lane == 1) ? lty
                                 : (lane == 2) ? ltw : lth;
                        float d = vlo - tv;
                        atomicAdd(&sacc[scale * 9 + lane], d * d);
                    }
                    if (lane == 4) atomicAdd(&sacc[scale * 9 + 4], bce1(vlo));
                }
            }
        }
        __syncthreads();
        if (threadIdx.x < 27) {
            float v = sacc[threadIdx.x];
            if (v != 0.0f) atomicAdd(&acc[threadIdx.x], v);
        }
    } else {
        // ---------------- noobj region: gather ch4 of every cell ----------------
        const int C0 = 8112, C01 = 40560, CT = 170352;
        int idx = (blockIdx.x - NCORR) * 256 + threadIdx.x;
        float s0 = 0.0f, s1 = 0.0f, s2 = 0.0f;
        if (idx < CT) {
            const float* p; int li, scale;
            if (idx < C0)       { p = o13; li = idx;       scale = 0; }
            else if (idx < C01) { p = o26; li = idx - C0;  scale = 1; }
            else                { p = o52; li = idx - C01; scale = 2; }
            float bv = bce0(p[(size_t)li * 85 + 4]);
            if (scale == 0) s0 = bv; else if (scale == 1) s1 = bv; else s2 = bv;
        }
        float v3[3] = { s0, s1, s2 };
        #pragma unroll
        for (int j = 0; j < 3; ++j) {
            float x = v3[j];
            #pragma unroll
            for (int off = 32; off; off >>= 1) x += __shfl_down(x, off);
            if (lane == 0) red[wvid][j] = x;
        }
        __syncthreads();
        if (threadIdx.x < 3) {
            float x = red[0][threadIdx.x] + red[1][threadIdx.x]
                    + red[2][threadIdx.x] + red[3][threadIdx.x];
            if (x != 0.0f) atomicAdd(&acc[threadIdx.x * 9 + 5], x);
        }
    }

    // ---------------- last-block finalize ----------------
    __syncthreads();                    // waves' atomics drained (vmcnt before barrier)
    if (threadIdx.x == 0) {
        __threadfence();
        unsigned old = atomicAdd(counter, 1u);
        sflag = (old == (unsigned)(NBLK - 1)) ? 1 : 0;
    }
    __syncthreads();
    if (sflag && threadIdx.x == 0) {
        __threadfence();
        float a[27];
        #pragma unroll
        for (int i = 0; i < 27; ++i) a[i] = atomicAdd(&acc[i], 0.0f);  // coherent read
        const float Stot0 = 8112.0f, Stot1 = 32448.0f, Stot2 = 129792.0f;
        float total = 0.0f;
        {
            float np = a[7], nn = Stot0 - a[8];
            total += a[0]/np + a[1]/np + a[2]/np + a[3]/np + a[4]/np
                   + a[5]/nn*100.0f + a[6]/(np*(float)NC);
        }
        {
            float np = a[16], nn = Stot1 - a[17];
            total += a[9]/np + a[10]/np + a[11]/np + a[12]/np + a[13]/np
                   + a[14]/nn*100.0f + a[15]/(np*(float)NC);
        }
        {
            float np = a[25], nn = Stot2 - a[26];
            total += a[18]/np + a[19]/np + a[20]/np + a[21]/np + a[22]/np
                   + a[23]/nn*100.0f + a[24]/(np*(float)NC);
        }
        outp[0] = total;
    }
}

extern "C" void kernel_launch(void* const* d_in, const int* in_sizes, int n_in,
                              void* d_out, int out_size, void* d_ws, size_t ws_size,
                              hipStream_t stream)
{
    const float* out13   = (const float*)d_in[0];
    const float* out26   = (const float*)d_in[1];
    const float* out52   = (const float*)d_in[2];
    const float* targets = (const float*)d_in[3];
    const float* a13     = (const float*)d_in[4];
    const float* a26     = (const float*)d_in[5];
    const float* a52     = (const float*)d_in[6];

    // ws: [0,108) acc[27]; [112,116) counter
    float*    acc     = (float*)d_ws;
    unsigned* counter = (unsigned*)((char*)d_ws + 112);

    hipMemsetAsync(d_ws, 0, 128, stream);

    fused_kernel<<<NBLK, 256, 0, stream>>>(
        out13, out26, out52, targets, a13, a26, a52, acc, counter, (float*)d_out);
}

// Round 5
// 26.613 us; speedup vs baseline: 1.8665x; 1.8665x over previous
//
#include <hip/hip_runtime.h>

// YOLOv3 loss on MI355X — round 5.
// Graph = memset(128B) + main kernel + tiny final kernel.
// Main kernel, blocks [0,600): correct — one wave per (scale,b,t); per-target
//   record recomputed IN-REGISTER; ballots/shuffles reconstruct mask/nm/
//   last-writer/class-union; coalesced 85-ch gather; lane-parallel class BCE.
// Main kernel, blocks [600,1266): noobj — gather ch4 of every cell.
// NO in-kernel finalize / __threadfence / counter (R4's 1266 device-scope
// release fences were the regression). final_kernel combines the 27 partials.

#define NB 16      // batch
#define NT 50      // targets per batch
#define NA 3       // anchors
#define NC 80      // classes
#define NCORR 600  // correct blocks (600*4 waves = 2400 = 3*16*50)
#define NBLK 1266  // total blocks (600 + ceil(170352/256))

__device__ __forceinline__ float bce0(float p) { return -log1pf(-p); } // target 0
__device__ __forceinline__ float bce1(float p) { return -logf(p); }    // target 1

// acc layout: [scale*9 + j], j: 0..3 mse, 4 obj, 5 noobj, 6 cls, 7 n_pos, 8 n_zeroed
__global__ __launch_bounds__(256) void main_kernel(
    const float* __restrict__ o13,
    const float* __restrict__ o26,
    const float* __restrict__ o52,
    const float* __restrict__ targets,
    const float* __restrict__ a13,
    const float* __restrict__ a26,
    const float* __restrict__ a52,
    float* __restrict__ acc)        // [27], zeroed by memset node
{
    __shared__ float sacc[27];
    __shared__ float red[4][3];

    int lane = threadIdx.x & 63;
    int wvid = threadIdx.x >> 6;

    if (blockIdx.x < NCORR) {
        // ---------------- correct region ----------------
        if (threadIdx.x < 27) sacc[threadIdx.x] = 0.0f;
        __syncthreads();

        int wid = blockIdx.x * 4 + wvid;            // 0..2399
        int scale = wid / (NB * NT);
        int rem   = wid - scale * (NB * NT);
        int b = rem / NT, t = rem - b * NT;

        int G = (scale == 0) ? 13 : (scale == 1) ? 26 : 52;
        const float* out  = (scale == 0) ? o13 : (scale == 1) ? o26 : o52;
        const float* anch = (scale == 0) ? a13 : (scale == 1) ? a26 : a52;

        // in-register build: lane l computes target l's record
        unsigned mt = 0xFFFFFFFFu;
        float tx = 0.0f, ty = 0.0f, tw = 0.0f, th = 0.0f;
        {
            int li = (lane < NT) ? lane : NT - 1;   // clamped addr, masked below
            const float* tg = targets + ((size_t)b * NT + li) * 5;
            float x1 = tg[0], y1 = tg[1], x2 = tg[2], y2 = tg[3];
            int cls = (int)tg[4];
            float gf = (float)G;
            float bx = 0.5f * (x1 + x2) * gf;
            float by = 0.5f * (y1 + y2) * gf;
            float bw = (x2 - x1) * gf;
            float bh = (y2 - y1) * gf;
            int best = 0; float bestiou = -1.0f, aw_b = 1.0f, ah_b = 1.0f;
            unsigned nmz = 0;
            #pragma unroll
            for (int a = 0; a < NA; ++a) {
                float aw = anch[2 * a], ah = anch[2 * a + 1];
                float inter = fminf(aw, bw) * fminf(ah, bh);
                float uni = 1e-8f + aw * ah + bw * bh - inter;
                float iou = inter / uni;
                if (iou > 0.5f) nmz |= (1u << a);
                if (iou > bestiou) { bestiou = iou; best = a; aw_b = aw; ah_b = ah; }
            }
            int gi = (int)bx; gi = gi < 0 ? 0 : (gi > G - 1 ? G - 1 : gi);
            int gj = (int)by; gj = gj < 0 ? 0 : (gj > G - 1 ? G - 1 : gj);
            tx = bx - floorf(bx);
            ty = by - floorf(by);
            tw = logf(bw / aw_b);
            th = logf(bh / ah_b);
            if (lane < NT)
                mt = (unsigned)gi | ((unsigned)gj << 6) | ((unsigned)best << 12)
                   | ((unsigned)cls << 14) | (nmz << 21);
        }

        unsigned key_lane = mt & 0xFFFu;
        unsigned key_t = __shfl(key_lane, t);
        unsigned long long match = __ballot(lane < NT && key_lane == key_t);
        bool canon = ((match & ((1ull << t) - 1ull)) == 0ull);   // wave-uniform

        if (canon) {
            int gi = key_t & 63, gj = (key_t >> 6) & 63;
            #pragma unroll
            for (int a = 0; a < NA; ++a) {
                unsigned long long bestmask =
                    __ballot(lane < NT && key_lane == key_t && (int)((mt >> 12) & 3u) == a);
                unsigned long long nmzmask =
                    __ballot(lane < NT && key_lane == key_t && ((mt >> (21 + a)) & 1u));
                bool pos = bestmask != 0ull;
                bool zeroed = pos || (nmzmask != 0ull);
                if (!zeroed) continue;                  // wave-uniform

                const float* pc = out + (((size_t)(b * NA + a) * G + gj) * G + gi) * 85;
                float vlo = pc[lane];                   // channels 0..63, coalesced
                if (lane == 4) {                        // noobj correction
                    atomicAdd(&sacc[scale * 9 + 5], -bce0(vlo));
                    atomicAdd(&sacc[scale * 9 + 8], 1.0f);
                }
                if (pos) {
                    float vhi = (lane < 21) ? pc[64 + lane] : 0.0f;  // ch 64..84
                    int lastt = 63 - __clzll(bestmask);  // last-write-wins
                    float ltx = __shfl(tx, lastt), lty = __shfl(ty, lastt);
                    float ltw = __shfl(tw, lastt), lth = __shfl(th, lastt);
                    // class-bit union across matching-best lanes
                    unsigned c0 = 0, c1 = 0, c2 = 0;
                    if ((bestmask >> lane) & 1ull) {
                        int c = (mt >> 14) & 127;
                        if (c < 32) c0 = 1u << c;
                        else if (c < 64) c1 = 1u << (c - 32);
                        else c2 = 1u << (c - 64);
                    }
                    #pragma unroll
                    for (int off = 32; off; off >>= 1) {
                        c0 |= __shfl_xor(c0, off);
                        c1 |= __shfl_xor(c1, off);
                        c2 |= __shfl_xor(c2, off);
                    }
                    // lane-parallel class BCE: lane -> channel lane and 64+lane
                    float cls = 0.0f;
                    if (lane >= 5) {
                        int c = lane - 5;               // 0..58
                        unsigned w = (c < 32) ? c0 : c1;
                        cls += ((w >> (c & 31)) & 1u) ? bce1(vlo) : bce0(vlo);
                    }
                    if (lane < 21) {
                        int c = lane + 59;              // 59..79
                        unsigned w = (c < 64) ? c1 : c2;
                        cls += ((w >> (c & 31)) & 1u) ? bce1(vhi) : bce0(vhi);
                    }
                    #pragma unroll
                    for (int off = 32; off; off >>= 1) cls += __shfl_xor(cls, off);
                    if (lane == 0) {
                        atomicAdd(&sacc[scale * 9 + 6], cls);
                        atomicAdd(&sacc[scale * 9 + 7], 1.0f);
                    }
                    if (lane < 4) {                     // mse terms
                        float tv = (lane == 0) ? ltx : (lane == 1) ? lty
                                 : (lane == 2) ? ltw : lth;
                        float d = vlo - tv;
                        atomicAdd(&sacc[scale * 9 + lane], d * d);
                    }
                    if (lane == 4) atomicAdd(&sacc[scale * 9 + 4], bce1(vlo));
                }
            }
        }
        __syncthreads();
        if (threadIdx.x < 27) {
            float v = sacc[threadIdx.x];
            if (v != 0.0f) atomicAdd(&acc[threadIdx.x], v);
        }
    } else {
        // ---------------- noobj region: gather ch4 of every cell ----------------
        const int C0 = 8112, C01 = 40560, CT = 170352;
        int idx = (blockIdx.x - NCORR) * 256 + threadIdx.x;
        float s0 = 0.0f, s1 = 0.0f, s2 = 0.0f;
        if (idx < CT) {
            const float* p; int li, scale;
            if (idx < C0)       { p = o13; li = idx;       scale = 0; }
            else if (idx < C01) { p = o26; li = idx - C0;  scale = 1; }
            else                { p = o52; li = idx - C01; scale = 2; }
            float bv = bce0(p[(size_t)li * 85 + 4]);
            if (scale == 0) s0 = bv; else if (scale == 1) s1 = bv; else s2 = bv;
        }
        float v3[3] = { s0, s1, s2 };
        #pragma unroll
        for (int j = 0; j < 3; ++j) {
            float x = v3[j];
            #pragma unroll
            for (int off = 32; off; off >>= 1) x += __shfl_down(x, off);
            if (lane == 0) red[wvid][j] = x;
        }
        __syncthreads();
        if (threadIdx.x < 3) {
            float x = red[0][threadIdx.x] + red[1][threadIdx.x]
                    + red[2][threadIdx.x] + red[3][threadIdx.x];
            if (x != 0.0f) atomicAdd(&acc[threadIdx.x * 9 + 5], x);
        }
    }
}

// ---------------- final: combine scales ----------------
__global__ void final_kernel(const float* __restrict__ acc, float* __restrict__ outp)
{
    const float Stot[3] = { 8112.0f, 32448.0f, 129792.0f };  // B*A*g*g
    float total = 0.0f;
    #pragma unroll
    for (int sidx = 0; sidx < 3; ++sidx) {
        const float* a = acc + sidx * 9;
        float np = a[7];
        float nn = Stot[sidx] - a[8];
        total += a[0]/np + a[1]/np + a[2]/np + a[3]/np + a[4]/np
               + a[5]/nn*100.0f + a[6]/(np*(float)NC);
    }
    outp[0] = total;
}

extern "C" void kernel_launch(void* const* d_in, const int* in_sizes, int n_in,
                              void* d_out, int out_size, void* d_ws, size_t ws_size,
                              hipStream_t stream)
{
    const float* out13   = (const float*)d_in[0];
    const float* out26   = (const float*)d_in[1];
    const float* out52   = (const float*)d_in[2];
    const float* targets = (const float*)d_in[3];
    const float* a13     = (const float*)d_in[4];
    const float* a26     = (const float*)d_in[5];
    const float* a52     = (const float*)d_in[6];

    float* acc = (float*)d_ws;          // 27 floats

    hipMemsetAsync(d_ws, 0, 128, stream);

    main_kernel<<<NBLK, 256, 0, stream>>>(
        out13, out26, out52, targets, a13, a26, a52, acc);

    final_kernel<<<1, 1, 0, stream>>>(acc, (float*)d_out);
}

// Round 6
// 25.955 us; speedup vs baseline: 1.9138x; 1.0254x over previous
//
#include <hip/hip_runtime.h>

// YOLOv3 loss on MI355X — round 6: 2-node graph, no memset, no atomics to HBM.
// main_kernel blocks [0,666):    noobj — gather ch4 of every cell (1/thread),
//                                scale chosen by block range (wave-uniform).
//            blocks [666,1266):  correct — one wave per (scale,b,t); in-register
//                                build; ballots/shuffles for mask/nm/last-writer/
//                                class-union; coalesced 85-ch gather.
// Every block writes 27 partial sums to slot[27][NBLK] (transposed for
// coalesced reads) -> no zero-init needed -> no memset node.
// final_kernel: 1 block, 256 threads, coalesced slot reduction + formula.

#define NB 16      // batch
#define NT 50      // targets per batch
#define NA 3       // anchors
#define NC 80      // classes
#define NNOOBJ 666 // noobj blocks: 32 (s0) + 127 (s1) + 507 (s2)
#define NBLK 1266  // total blocks (666 noobj + 600 correct)

__device__ __forceinline__ float bce0(float p) { return -log1pf(-p); } // target 0
__device__ __forceinline__ float bce1(float p) { return -logf(p); }    // target 1

// slot row layout j: scale*9 + {0..3 mse, 4 obj, 5 noobj, 6 cls, 7 n_pos, 8 n_zeroed}
__global__ __launch_bounds__(256) void main_kernel(
    const float* __restrict__ o13,
    const float* __restrict__ o26,
    const float* __restrict__ o52,
    const float* __restrict__ targets,
    const float* __restrict__ a13,
    const float* __restrict__ a26,
    const float* __restrict__ a52,
    float* __restrict__ slot)       // [27][NBLK]
{
    __shared__ float sacc[27];
    __shared__ float red4[4];

    int lane = threadIdx.x & 63;
    int wvid = threadIdx.x >> 6;

    if (blockIdx.x < NNOOBJ) {
        // ---------------- noobj region: gather ch4 of every cell ----------------
        int bi = blockIdx.x;
        const float* p; int li, cnt, scale;
        if (bi < 32)       { p = o13; scale = 0; li = bi * 256 + threadIdx.x;         cnt = 8112;   }
        else if (bi < 159) { p = o26; scale = 1; li = (bi - 32) * 256 + threadIdx.x;  cnt = 32448;  }
        else               { p = o52; scale = 2; li = (bi - 159) * 256 + threadIdx.x; cnt = 129792; }
        float bv = (li < cnt) ? bce0(p[(size_t)li * 85 + 4]) : 0.0f;
        #pragma unroll
        for (int off = 32; off; off >>= 1) bv += __shfl_down(bv, off);
        if (lane == 0) red4[wvid] = bv;
        __syncthreads();
        if (threadIdx.x < 27) {
            float x = 0.0f;
            if ((int)threadIdx.x == scale * 9 + 5)
                x = red4[0] + red4[1] + red4[2] + red4[3];
            slot[threadIdx.x * NBLK + blockIdx.x] = x;
        }
        return;
    }

    // ---------------- correct region ----------------
    if (threadIdx.x < 27) sacc[threadIdx.x] = 0.0f;
    __syncthreads();

    int wid = (blockIdx.x - NNOOBJ) * 4 + wvid;     // 0..2399
    int scale = wid / (NB * NT);
    int rem   = wid - scale * (NB * NT);
    int b = rem / NT, t = rem - b * NT;

    int G = (scale == 0) ? 13 : (scale == 1) ? 26 : 52;
    const float* out  = (scale == 0) ? o13 : (scale == 1) ? o26 : o52;
    const float* anch = (scale == 0) ? a13 : (scale == 1) ? a26 : a52;

    // in-register build: lane l computes target l's record
    unsigned mt = 0xFFFFFFFFu;
    float tx = 0.0f, ty = 0.0f, tw = 0.0f, th = 0.0f;
    {
        int li = (lane < NT) ? lane : NT - 1;       // clamped addr, masked below
        const float* tg = targets + ((size_t)b * NT + li) * 5;
        float x1 = tg[0], y1 = tg[1], x2 = tg[2], y2 = tg[3];
        int cls = (int)tg[4];
        float gf = (float)G;
        float bx = 0.5f * (x1 + x2) * gf;
        float by = 0.5f * (y1 + y2) * gf;
        float bw = (x2 - x1) * gf;
        float bh = (y2 - y1) * gf;
        int best = 0; float bestiou = -1.0f, aw_b = 1.0f, ah_b = 1.0f;
        unsigned nmz = 0;
        #pragma unroll
        for (int a = 0; a < NA; ++a) {
            float aw = anch[2 * a], ah = anch[2 * a + 1];
            float inter = fminf(aw, bw) * fminf(ah, bh);
            float uni = 1e-8f + aw * ah + bw * bh - inter;
            float iou = inter / uni;
            if (iou > 0.5f) nmz |= (1u << a);
            if (iou > bestiou) { bestiou = iou; best = a; aw_b = aw; ah_b = ah; }
        }
        int gi = (int)bx; gi = gi < 0 ? 0 : (gi > G - 1 ? G - 1 : gi);
        int gj = (int)by; gj = gj < 0 ? 0 : (gj > G - 1 ? G - 1 : gj);
        tx = bx - floorf(bx);
        ty = by - floorf(by);
        tw = logf(bw / aw_b);
        th = logf(bh / ah_b);
        if (lane < NT)
            mt = (unsigned)gi | ((unsigned)gj << 6) | ((unsigned)best << 12)
               | ((unsigned)cls << 14) | (nmz << 21);
    }

    unsigned key_lane = mt & 0xFFFu;
    unsigned key_t = __shfl(key_lane, t);
    unsigned long long match = __ballot(lane < NT && key_lane == key_t);
    bool canon = ((match & ((1ull << t) - 1ull)) == 0ull);   // wave-uniform

    if (canon) {
        int gi = key_t & 63, gj = (key_t >> 6) & 63;
        #pragma unroll
        for (int a = 0; a < NA; ++a) {
            unsigned long long bestmask =
                __ballot(lane < NT && key_lane == key_t && (int)((mt >> 12) & 3u) == a);
            unsigned long long nmzmask =
                __ballot(lane < NT && key_lane == key_t && ((mt >> (21 + a)) & 1u));
            bool pos = bestmask != 0ull;
            bool zeroed = pos || (nmzmask != 0ull);
            if (!zeroed) continue;                  // wave-uniform

            const float* pc = out + (((size_t)(b * NA + a) * G + gj) * G + gi) * 85;
            float vlo = pc[lane];                   // channels 0..63, coalesced
            if (lane == 4) {                        // noobj correction
                atomicAdd(&sacc[scale * 9 + 5], -bce0(vlo));
                atomicAdd(&sacc[scale * 9 + 8], 1.0f);
            }
            if (pos) {
                float vhi = (lane < 21) ? pc[64 + lane] : 0.0f;  // ch 64..84
                int lastt = 63 - __clzll(bestmask);  // last-write-wins
                float ltx = __shfl(tx, lastt), lty = __shfl(ty, lastt);
                float ltw = __shfl(tw, lastt), lth = __shfl(th, lastt);
                // class-bit union across matching-best lanes
                unsigned c0 = 0, c1 = 0, c2 = 0;
                if ((bestmask >> lane) & 1ull) {
                    int c = (mt >> 14) & 127;
                    if (c < 32) c0 = 1u << c;
                    else if (c < 64) c1 = 1u << (c - 32);
                    else c2 = 1u << (c - 64);
                }
                #pragma unroll
                for (int off = 32; off; off >>= 1) {
                    c0 |= __shfl_xor(c0, off);
                    c1 |= __shfl_xor(c1, off);
                    c2 |= __shfl_xor(c2, off);
                }
                // lane-parallel class BCE: lane -> channel lane and 64+lane
                float cls = 0.0f;
                if (lane >= 5) {
                    int c = lane - 5;               // 0..58
                    unsigned w = (c < 32) ? c0 : c1;
                    cls += ((w >> (c & 31)) & 1u) ? bce1(vlo) : bce0(vlo);
                }
                if (lane < 21) {
                    int c = lane + 59;              // 59..79
                    unsigned w = (c < 64) ? c1 : c2;
                    cls += ((w >> (c & 31)) & 1u) ? bce1(vhi) : bce0(vhi);
                }
                #pragma unroll
                for (int off = 32; off; off >>= 1) cls += __shfl_xor(cls, off);
                if (lane == 0) {
                    atomicAdd(&sacc[scale * 9 + 6], cls);
                    atomicAdd(&sacc[scale * 9 + 7], 1.0f);
                }
                if (lane < 4) {                     // mse terms
                    float tv = (lane == 0) ? ltx : (lane == 1) ? lty
                             : (lane == 2) ? ltw : lth;
                    float d = vlo - tv;
                    atomicAdd(&sacc[scale * 9 + lane], d * d);
                }
                if (lane == 4) atomicAdd(&sacc[scale * 9 + 4], bce1(vlo));
            }
        }
    }
    __syncthreads();
    if (threadIdx.x < 27)
        slot[threadIdx.x * NBLK + blockIdx.x] = sacc[threadIdx.x];
}

// ---------------- final: reduce slots + combine scales ----------------
__global__ __launch_bounds__(256) void final_kernel(
    const float* __restrict__ slot, float* __restrict__ outp)
{
    float s[27];
    #pragma unroll
    for (int j = 0; j < 27; ++j) s[j] = 0.0f;
    for (int bk = threadIdx.x; bk < NBLK; bk += 256) {
        #pragma unroll
        for (int j = 0; j < 27; ++j) s[j] += slot[j * NBLK + bk];   // coalesced
    }
    __shared__ float red[4][27];
    int lane = threadIdx.x & 63, wv = threadIdx.x >> 6;
    #pragma unroll
    for (int j = 0; j < 27; ++j) {
        float x = s[j];
        #pragma unroll
        for (int off = 32; off; off >>= 1) x += __shfl_down(x, off);
        if (lane == 0) red[wv][j] = x;
    }
    __syncthreads();
    if (threadIdx.x == 0) {
        float a[27];
        #pragma unroll
        for (int j = 0; j < 27; ++j)
            a[j] = red[0][j] + red[1][j] + red[2][j] + red[3][j];
        const float Stot0 = 8112.0f, Stot1 = 32448.0f, Stot2 = 129792.0f;
        float total = 0.0f;
        {
            float np = a[7],  nn = Stot0 - a[8];
            total += a[0]/np + a[1]/np + a[2]/np + a[3]/np + a[4]/np
                   + a[5]/nn*100.0f + a[6]/(np*(float)NC);
        }
        {
            float np = a[16], nn = Stot1 - a[17];
            total += a[9]/np + a[10]/np + a[11]/np + a[12]/np + a[13]/np
                   + a[14]/nn*100.0f + a[15]/(np*(float)NC);
        }
        {
            float np = a[25], nn = Stot2 - a[26];
            total += a[18]/np + a[19]/np + a[20]/np + a[21]/np + a[22]/np
                   + a[23]/nn*100.0f + a[24]/(np*(float)NC);
        }
        outp[0] = total;
    }
}

extern "C" void kernel_launch(void* const* d_in, const int* in_sizes, int n_in,
                              void* d_out, int out_size, void* d_ws, size_t ws_size,
                              hipStream_t stream)
{
    const float* out13   = (const float*)d_in[0];
    const float* out26   = (const float*)d_in[1];
    const float* out52   = (const float*)d_in[2];
    const float* targets = (const float*)d_in[3];
    const float* a13     = (const float*)d_in[4];
    const float* a26     = (const float*)d_in[5];
    const float* a52     = (const float*)d_in[6];

    float* slot = (float*)d_ws;     // [27][NBLK] = 136728 B

    main_kernel<<<NBLK, 256, 0, stream>>>(
        out13, out26, out52, targets, a13, a26, a52, slot);

    final_kernel<<<1, 256, 0, stream>>>(slot, (float*)d_out);
}